// Round 1
// baseline (313.401 us; speedup 1.0000x reference)
//
#include <hip/hip_runtime.h>
#include <cstdint>
#include <cstddef>

// Problem constants (fixed by the reference)
#define NB 8
#define NA 100000
#define NM 32
#define NC 80

// ws layout:
//   offset 0:   float cls_sum[NB]
//   offset 32:  float reg_sum[NB]
//   offset 64:  unsigned num_pos[NB]
//   offset 128: uint8_t state[NB*NA]   (class 0..79 = pos, 200 = neg, 201 = ignore)

__global__ __launch_bounds__(256) void assign_kernel(
    const float* __restrict__ anchors,   // [NA,4]
    const float* __restrict__ annots,    // [NB,NM,5]
    const float* __restrict__ regs,      // [NB,NA,4]
    uint8_t* __restrict__ state,         // [NB*NA]
    float* __restrict__ reg_sum,         // [NB]
    unsigned* __restrict__ num_pos)      // [NB]
{
    const int b = blockIdx.y;
    const int a = blockIdx.x * 256 + threadIdx.x;

    __shared__ float sann[NM * 5];
    if (threadIdx.x < NM * 5) sann[threadIdx.x] = annots[b * NM * 5 + threadIdx.x];
    __syncthreads();

    float my_reg = 0.f;
    int   my_pos = 0;

    if (a < NA) {
        const float4 av = reinterpret_cast<const float4*>(anchors)[a];
        const float ax1 = av.x, ay1 = av.y, ax2 = av.z, ay2 = av.w;
        const float aw = ax2 - ax1, ah = ay2 - ay1;
        const float aarea = aw * ah;

        float best = -1e30f;
        int   barg = 0;
        #pragma unroll
        for (int m = 0; m < NM; ++m) {
            const float bx1 = sann[m * 5 + 0];
            const float by1 = sann[m * 5 + 1];
            const float bx2 = sann[m * 5 + 2];
            const float by2 = sann[m * 5 + 3];
            const float bc  = sann[m * 5 + 4];
            const float area = (bx2 - bx1) * (by2 - by1);
            float iw = fminf(ax2, bx2) - fmaxf(ax1, bx1);
            float ih = fminf(ay2, by2) - fmaxf(ay1, by1);
            iw = fmaxf(iw, 0.f);
            ih = fmaxf(ih, 0.f);
            const float inter = iw * ih;
            const float ua = fmaxf(aarea + area - inter, 1e-8f);
            float iou = inter / ua;
            if (bc == -1.0f) iou = -1.0f;      // mask padded annotations
            if (iou > best) { best = iou; barg = m; }  // first-max, matches argmax
        }

        uint8_t st = 201;                       // ignore by default
        if (best >= 0.5f) {
            const float bx1 = sann[barg * 5 + 0];
            const float by1 = sann[barg * 5 + 1];
            const float bx2 = sann[barg * 5 + 2];
            const float by2 = sann[barg * 5 + 3];
            const int   k   = (int)sann[barg * 5 + 4];
            st = (uint8_t)k;
            my_pos = 1;
            // regression target
            const float gw  = fmaxf(bx2 - bx1, 0.f);
            const float gh  = fmaxf(by2 - by1, 0.f);
            const float gcx = bx1 + 0.5f * (bx2 - bx1);
            const float gcy = by1 + 0.5f * (by2 - by1);
            const float acx = ax1 + 0.5f * aw;
            const float acy = ay1 + 0.5f * ah;
            const float t0 = ((gcx - acx) / aw) / 0.1f;
            const float t1 = ((gcy - acy) / ah) / 0.1f;
            const float t2 = __logf(gw / aw) / 0.2f;
            const float t3 = __logf(gh / ah) / 0.2f;
            const float4 rp = reinterpret_cast<const float4*>(regs)[(size_t)b * NA + a];
            const float d0 = fabsf(t0 - rp.x);
            const float d1 = fabsf(t1 - rp.y);
            const float d2 = fabsf(t2 - rp.z);
            const float d3 = fabsf(t3 - rp.w);
            const float TH = 1.f / 9.f;
            const float C59 = 5.f / 9.f;
            my_reg  = (d0 <= TH) ? 4.5f * d0 * d0 : d0 - C59;
            my_reg += (d1 <= TH) ? 4.5f * d1 * d1 : d1 - C59;
            my_reg += (d2 <= TH) ? 4.5f * d2 * d2 : d2 - C59;
            my_reg += (d3 <= TH) ? 4.5f * d3 * d3 : d3 - C59;
        } else if (best < 0.4f) {
            st = 200;                           // negative
        }
        state[(size_t)b * NA + a] = st;
    }

    // 64-lane wave reduction, one atomic per wave
    #pragma unroll
    for (int off = 32; off; off >>= 1) {
        my_reg += __shfl_down(my_reg, off);
        my_pos += __shfl_down(my_pos, off);
    }
    if ((threadIdx.x & 63) == 0) {
        atomicAdd(&reg_sum[b], my_reg);
        atomicAdd(&num_pos[b], (unsigned)my_pos);
    }
}

__global__ __launch_bounds__(256) void cls_kernel(
    const float* __restrict__ cls,       // [NB,NA,NC]
    const uint8_t* __restrict__ state,   // [NB*NA]
    float* __restrict__ cls_sum)         // [NB]
{
    const int b = blockIdx.y;
    const float4* __restrict__ p4 = reinterpret_cast<const float4*>(cls + (size_t)b * NA * NC);
    const uint8_t* __restrict__ stb = state + (size_t)b * NA;
    const int n4 = NA * NC / 4;          // 2,000,000 float4 per image

    float acc = 0.f;
    for (int i = blockIdx.x * 256 + threadIdx.x; i < n4; i += gridDim.x * 256) {
        const float4 v = p4[i];
        const int a  = i / (NC / 4);            // /20 -> magic mul
        const int c0 = (i - a * (NC / 4)) * 4;  // class index of v.x
        const int st = stb[a];
        if (st == 201) continue;                // ignore anchor: all targets == -1
        const float pv[4] = {v.x, v.y, v.z, v.w};
        #pragma unroll
        for (int j = 0; j < 4; ++j) {
            const float p = fminf(fmaxf(pv[j], 1e-4f), 0.9999f);
            const bool is_t = (st < NC) && (c0 + j == st);
            const float fw = is_t ? (1.f - p) : p;
            const float af = is_t ? 0.25f : 0.75f;
            const float lg = is_t ? __logf(p) : __logf(1.f - p);
            acc += af * fw * fw * (-lg);
        }
    }

    #pragma unroll
    for (int off = 32; off; off >>= 1) acc += __shfl_down(acc, off);
    if ((threadIdx.x & 63) == 0) atomicAdd(&cls_sum[b], acc);
}

__global__ void finalize_kernel(
    const float* __restrict__ annots,    // [NB,NM,5]
    const float* __restrict__ cls_sum,
    const float* __restrict__ reg_sum,
    const unsigned* __restrict__ num_pos,
    float* __restrict__ out)
{
    if (threadIdx.x == 0 && blockIdx.x == 0) {
        float cm = 0.f, rm = 0.f;
        for (int b = 0; b < NB; ++b) {
            bool hv = false;
            for (int m = 0; m < NM; ++m)
                hv = hv || (annots[b * NM * 5 + m * 5 + 4] != -1.0f);
            const unsigned npu = num_pos[b];
            const float d = fmaxf((float)npu, 1.f);
            cm += hv ? cls_sum[b] / d : 0.f;
            rm += (npu > 0) ? reg_sum[b] / (4.f * d) : 0.f;
        }
        out[0] = cm / (float)NB;
        out[1] = rm / (float)NB;
    }
}

extern "C" void kernel_launch(void* const* d_in, const int* in_sizes, int n_in,
                              void* d_out, int out_size, void* d_ws, size_t ws_size,
                              hipStream_t stream) {
    const float* cls     = (const float*)d_in[0];  // [NB,NA,NC]
    const float* regs    = (const float*)d_in[1];  // [NB,NA,4]
    const float* anchors = (const float*)d_in[2];  // [1,NA,4]
    const float* annots  = (const float*)d_in[3];  // [NB,NM,5]
    float* out = (float*)d_out;

    float*    cls_sum = (float*)d_ws;
    float*    reg_sum = cls_sum + NB;
    unsigned* num_pos = (unsigned*)(reg_sum + NB);
    uint8_t*  state   = (uint8_t*)d_ws + 128;

    // zero the 96B accumulator region (deterministic per call; capture-legal)
    hipMemsetAsync(d_ws, 0, 128, stream);

    dim3 g1((NA + 255) / 256, NB);
    assign_kernel<<<g1, 256, 0, stream>>>(anchors, annots, regs, state, reg_sum, num_pos);

    dim3 g2(256, NB);  // 2048 blocks total, grid-stride
    cls_kernel<<<g2, 256, 0, stream>>>(cls, state, cls_sum);

    finalize_kernel<<<1, 64, 0, stream>>>(annots, cls_sum, reg_sum, num_pos, out);
}

// Round 2
// 302.703 us; speedup vs baseline: 1.0353x; 1.0353x over previous
//
#include <hip/hip_runtime.h>
#include <cstdint>
#include <cstddef>

// Problem constants (fixed by the reference)
#define NB 8
#define NA 100000
#define NM 32
#define NC 80
#define GX 256   // blocks per image for cls_kernel (grid = GX x NB)

// ws layout:
//   offset 0:   float cls_sum[NB]
//   offset 32:  float reg_sum[NB]
//   offset 64:  unsigned num_pos[NB]
//   offset 128: uint8_t state[NB*NA]   (class 0..79 = pos, 200 = neg, 201 = ignore)

__global__ __launch_bounds__(256) void assign_kernel(
    const float* __restrict__ anchors,   // [NA,4]
    const float* __restrict__ annots,    // [NB,NM,5]
    const float* __restrict__ regs,      // [NB,NA,4]
    uint8_t* __restrict__ state,         // [NB*NA]
    float* __restrict__ reg_sum,         // [NB]
    unsigned* __restrict__ num_pos)      // [NB]
{
    const int b = blockIdx.y;
    const int a = blockIdx.x * 256 + threadIdx.x;

    __shared__ float sann[NM * 5];
    if (threadIdx.x < NM * 5) sann[threadIdx.x] = annots[b * NM * 5 + threadIdx.x];
    __syncthreads();

    float my_reg = 0.f;
    int   my_pos = 0;

    if (a < NA) {
        const float4 av = reinterpret_cast<const float4*>(anchors)[a];
        const float ax1 = av.x, ay1 = av.y, ax2 = av.z, ay2 = av.w;
        const float aw = ax2 - ax1, ah = ay2 - ay1;
        const float aarea = aw * ah;

        float best = -1e30f;
        int   barg = 0;
        #pragma unroll
        for (int m = 0; m < NM; ++m) {
            const float bx1 = sann[m * 5 + 0];
            const float by1 = sann[m * 5 + 1];
            const float bx2 = sann[m * 5 + 2];
            const float by2 = sann[m * 5 + 3];
            const float bc  = sann[m * 5 + 4];
            const float area = (bx2 - bx1) * (by2 - by1);
            float iw = fminf(ax2, bx2) - fmaxf(ax1, bx1);
            float ih = fminf(ay2, by2) - fmaxf(ay1, by1);
            iw = fmaxf(iw, 0.f);
            ih = fmaxf(ih, 0.f);
            const float inter = iw * ih;
            const float ua = fmaxf(aarea + area - inter, 1e-8f);
            float iou = inter / ua;
            if (bc == -1.0f) iou = -1.0f;      // mask padded annotations
            if (iou > best) { best = iou; barg = m; }  // first-max, matches argmax
        }

        uint8_t st = 201;                       // ignore by default
        if (best >= 0.5f) {
            const float bx1 = sann[barg * 5 + 0];
            const float by1 = sann[barg * 5 + 1];
            const float bx2 = sann[barg * 5 + 2];
            const float by2 = sann[barg * 5 + 3];
            const int   k   = (int)sann[barg * 5 + 4];
            st = (uint8_t)k;
            my_pos = 1;
            // regression target
            const float gw  = fmaxf(bx2 - bx1, 0.f);
            const float gh  = fmaxf(by2 - by1, 0.f);
            const float gcx = bx1 + 0.5f * (bx2 - bx1);
            const float gcy = by1 + 0.5f * (by2 - by1);
            const float acx = ax1 + 0.5f * aw;
            const float acy = ay1 + 0.5f * ah;
            const float t0 = ((gcx - acx) / aw) / 0.1f;
            const float t1 = ((gcy - acy) / ah) / 0.1f;
            const float t2 = __logf(gw / aw) / 0.2f;
            const float t3 = __logf(gh / ah) / 0.2f;
            const float4 rp = reinterpret_cast<const float4*>(regs)[(size_t)b * NA + a];
            const float d0 = fabsf(t0 - rp.x);
            const float d1 = fabsf(t1 - rp.y);
            const float d2 = fabsf(t2 - rp.z);
            const float d3 = fabsf(t3 - rp.w);
            const float TH = 1.f / 9.f;
            const float C59 = 5.f / 9.f;
            my_reg  = (d0 <= TH) ? 4.5f * d0 * d0 : d0 - C59;
            my_reg += (d1 <= TH) ? 4.5f * d1 * d1 : d1 - C59;
            my_reg += (d2 <= TH) ? 4.5f * d2 * d2 : d2 - C59;
            my_reg += (d3 <= TH) ? 4.5f * d3 * d3 : d3 - C59;
        } else if (best < 0.4f) {
            st = 200;                           // negative
        }
        state[(size_t)b * NA + a] = st;
    }

    // 64-lane wave reduction, one atomic per wave
    #pragma unroll
    for (int off = 32; off; off >>= 1) {
        my_reg += __shfl_down(my_reg, off);
        my_pos += __shfl_down(my_pos, off);
    }
    if ((threadIdx.x & 63) == 0) {
        atomicAdd(&reg_sum[b], my_reg);
        atomicAdd(&num_pos[b], (unsigned)my_pos);
    }
}

// Focal loss over [NA,NC] probabilities, one image per blockIdx.y.
// Uniform negative formula for all non-ignored elements:
//   term_neg = 0.75 * p^2 * (-log(1-p))   -> accumulate s = p^2*log(1-p), scale by -0.75 at end
// Rare correction at the single target element of positive anchors:
//   corr = 0.25*(1-p)^2*(-log p) - 0.75*p^2*(-log(1-p))
// 4-deep explicit batching for memory-level parallelism (the R0 kernel was
// latency-bound: VGPR=16, MLP~1, 36% VALU, 9% HBM).
__global__ __launch_bounds__(256) void cls_kernel(
    const float* __restrict__ cls,       // [NB,NA,NC]
    const uint8_t* __restrict__ state,   // [NB*NA]
    float* __restrict__ cls_sum)         // [NB]
{
    const int b = blockIdx.y;
    const float4* __restrict__ p4 = reinterpret_cast<const float4*>(cls + (size_t)b * NA * NC);
    const uint8_t* __restrict__ stb = state + (size_t)b * NA;
    constexpr int n4 = NA * NC / 4;      // 2,000,000 float4 per image
    constexpr int STRIDE = GX * 256;     // 65536

    float accn = 0.f;  // sum of p^2 * log(1-p) over non-ignored elements (negative values)
    float accp = 0.f;  // corrections for target elements

    const int tid = blockIdx.x * 256 + threadIdx.x;
    for (int i0 = tid; i0 < n4; i0 += 4 * STRIDE) {
        int    idx[4];
        bool   val[4];
        float4 v[4];
        int    st[4];
        int    c0[4];
        #pragma unroll
        for (int k = 0; k < 4; ++k) {
            const int i = i0 + k * STRIDE;
            val[k] = (i < n4);
            idx[k] = val[k] ? i : (n4 - 1);
        }
        #pragma unroll
        for (int k = 0; k < 4; ++k) v[k] = p4[idx[k]];           // 4 independent loads in flight
        #pragma unroll
        for (int k = 0; k < 4; ++k) {
            const int a = idx[k] / (NC / 4);
            c0[k] = (idx[k] - a * (NC / 4)) * 4;
            st[k] = stb[a];
        }
        #pragma unroll
        for (int k = 0; k < 4; ++k) {
            const int  s   = st[k];
            const bool act = val[k] && (s != 201);
            const float pv[4] = {v[k].x, v[k].y, v[k].z, v[k].w};
            float g = 0.f;
            #pragma unroll
            for (int j = 0; j < 4; ++j) {
                const float p  = fminf(fmaxf(pv[j], 1e-4f), 0.9999f);
                const float om = 1.f - p;
                const float l1 = __logf(om);            // log(1-p) <= 0
                g = __fmaf_rn(p * p, l1, g);
                if (val[k] && (s < NC) && (c0[k] + j == s)) {
                    const float lp = __logf(p);
                    accp += 0.25f * om * om * (-lp) + 0.75f * (p * p) * l1;
                }
            }
            accn += act ? g : 0.f;
        }
    }

    float acc = __fmaf_rn(-0.75f, accn, accp);
    #pragma unroll
    for (int off = 32; off; off >>= 1) acc += __shfl_down(acc, off);
    if ((threadIdx.x & 63) == 0) atomicAdd(&cls_sum[b], acc);
}

__global__ void finalize_kernel(
    const float* __restrict__ annots,    // [NB,NM,5]
    const float* __restrict__ cls_sum,
    const float* __restrict__ reg_sum,
    const unsigned* __restrict__ num_pos,
    float* __restrict__ out)
{
    if (threadIdx.x == 0 && blockIdx.x == 0) {
        float cm = 0.f, rm = 0.f;
        for (int b = 0; b < NB; ++b) {
            bool hv = false;
            for (int m = 0; m < NM; ++m)
                hv = hv || (annots[b * NM * 5 + m * 5 + 4] != -1.0f);
            const unsigned npu = num_pos[b];
            const float d = fmaxf((float)npu, 1.f);
            cm += hv ? cls_sum[b] / d : 0.f;
            rm += (npu > 0) ? reg_sum[b] / (4.f * d) : 0.f;
        }
        out[0] = cm / (float)NB;
        out[1] = rm / (float)NB;
    }
}

extern "C" void kernel_launch(void* const* d_in, const int* in_sizes, int n_in,
                              void* d_out, int out_size, void* d_ws, size_t ws_size,
                              hipStream_t stream) {
    const float* cls     = (const float*)d_in[0];  // [NB,NA,NC]
    const float* regs    = (const float*)d_in[1];  // [NB,NA,4]
    const float* anchors = (const float*)d_in[2];  // [1,NA,4]
    const float* annots  = (const float*)d_in[3];  // [NB,NM,5]
    float* out = (float*)d_out;

    float*    cls_sum = (float*)d_ws;
    float*    reg_sum = cls_sum + NB;
    unsigned* num_pos = (unsigned*)(reg_sum + NB);
    uint8_t*  state   = (uint8_t*)d_ws + 128;

    // zero the 96B accumulator region (deterministic per call; capture-legal)
    hipMemsetAsync(d_ws, 0, 128, stream);

    dim3 g1((NA + 255) / 256, NB);
    assign_kernel<<<g1, 256, 0, stream>>>(anchors, annots, regs, state, reg_sum, num_pos);

    dim3 g2(GX, NB);  // 2048 blocks total, grid-stride with 4-deep batching
    cls_kernel<<<g2, 256, 0, stream>>>(cls, state, cls_sum);

    finalize_kernel<<<1, 64, 0, stream>>>(annots, cls_sum, reg_sum, num_pos, out);
}

// Round 3
// 105.670 us; speedup vs baseline: 2.9658x; 2.8646x over previous
//
#include <hip/hip_runtime.h>
#include <cstdint>
#include <cstddef>

// Problem constants (fixed by the reference)
#define NB 8
#define NA 100000
#define NM 32
#define NC 80
#define BLK 256
#define NBLK ((NA + BLK - 1) / BLK)   // 391 blocks per image

// ws layout: float4 parts[NB][NBLK] = {cls_sum, reg_sum, num_pos, 0} per block.
// Every block writes its slot unconditionally -> no zero-init, no atomics.

__global__ __launch_bounds__(256) void fused_kernel(
    const float* __restrict__ cls,       // [NB,NA,NC]
    const float* __restrict__ regs,      // [NB,NA,4]
    const float* __restrict__ anchors,   // [NA,4]
    const float* __restrict__ annots,    // [NB,NM,5]
    float4* __restrict__ parts)          // [NB*NBLK]
{
    const int b   = blockIdx.y;
    const int blk = blockIdx.x;
    const int tid = threadIdx.x;
    const int a   = blk * BLK + tid;

    __shared__ float sann[NM * 5];
    __shared__ int   sstate[BLK];        // class 0..79 = pos, 200 = neg, 201 = ignore
    __shared__ float sred[4 * 3];        // 4 waves x {cls, reg, pos}

    if (tid < NM * 5) sann[tid] = annots[b * NM * 5 + tid];
    __syncthreads();

    // ---- Phase 1: per-thread anchor assignment + regression loss ----
    float reg_acc = 0.f;
    float posf    = 0.f;
    int   st      = 201;

    if (a < NA) {
        const float4 av = reinterpret_cast<const float4*>(anchors)[a];
        const float ax1 = av.x, ay1 = av.y, ax2 = av.z, ay2 = av.w;
        const float aw = ax2 - ax1, ah = ay2 - ay1;
        const float aarea = aw * ah;

        float best = -1e30f;
        int   barg = 0;
        #pragma unroll
        for (int m = 0; m < NM; ++m) {
            const float bx1 = sann[m * 5 + 0];
            const float by1 = sann[m * 5 + 1];
            const float bx2 = sann[m * 5 + 2];
            const float by2 = sann[m * 5 + 3];
            const float bc  = sann[m * 5 + 4];
            const float area = (bx2 - bx1) * (by2 - by1);
            float iw = fminf(ax2, bx2) - fmaxf(ax1, bx1);
            float ih = fminf(ay2, by2) - fmaxf(ay1, by1);
            iw = fmaxf(iw, 0.f);
            ih = fmaxf(ih, 0.f);
            const float inter = iw * ih;
            const float ua = fmaxf(aarea + area - inter, 1e-8f);
            float iou = inter * __builtin_amdgcn_rcpf(ua);   // fast rcp: feeds thresholds only
            if (bc == -1.0f) iou = -1.0f;                    // mask padded annotations
            if (iou > best) { best = iou; barg = m; }        // first-max == jnp.argmax
        }

        if (best >= 0.5f) {
            const float bx1 = sann[barg * 5 + 0];
            const float by1 = sann[barg * 5 + 1];
            const float bx2 = sann[barg * 5 + 2];
            const float by2 = sann[barg * 5 + 3];
            st   = (int)sann[barg * 5 + 4];
            posf = 1.f;
            const float gw  = fmaxf(bx2 - bx1, 0.f);
            const float gh  = fmaxf(by2 - by1, 0.f);
            const float gcx = bx1 + 0.5f * (bx2 - bx1);
            const float gcy = by1 + 0.5f * (by2 - by1);
            const float acx = ax1 + 0.5f * aw;
            const float acy = ay1 + 0.5f * ah;
            const float t0 = ((gcx - acx) / aw) * 10.f;
            const float t1 = ((gcy - acy) / ah) * 10.f;
            const float t2 = __logf(gw / aw) * 5.f;
            const float t3 = __logf(gh / ah) * 5.f;
            const float4 rp = reinterpret_cast<const float4*>(regs)[(size_t)b * NA + a];
            const float d0 = fabsf(t0 - rp.x);
            const float d1 = fabsf(t1 - rp.y);
            const float d2 = fabsf(t2 - rp.z);
            const float d3 = fabsf(t3 - rp.w);
            const float TH = 1.f / 9.f;
            const float C59 = 5.f / 9.f;
            reg_acc  = (d0 <= TH) ? 4.5f * d0 * d0 : d0 - C59;
            reg_acc += (d1 <= TH) ? 4.5f * d1 * d1 : d1 - C59;
            reg_acc += (d2 <= TH) ? 4.5f * d2 * d2 : d2 - C59;
            reg_acc += (d3 <= TH) ? 4.5f * d3 * d3 : d3 - C59;
        } else if (best < 0.4f) {
            st = 200;
        }
    }
    sstate[tid] = st;
    __syncthreads();

    // ---- Phase 2: cooperative focal-loss scan of this block's 256x80 span ----
    // Uniform negative term 0.75*p^2*(-log(1-p)) for every non-ignored element;
    // rare correction at the single target element of positive anchors.
    const int na_blk = min(BLK, NA - blk * BLK);
    const float4* __restrict__ p4 =
        reinterpret_cast<const float4*>(cls) + ((size_t)b * NA + (size_t)blk * BLK) * (NC / 4);

    float accn = 0.f;   // sum p^2 * log(1-p) over non-ignored
    float accp = 0.f;   // target-element corrections

    auto body = [&](int i) {
        const float4 v = p4[i];
        const int al = i / (NC / 4);            // local anchor
        const int c0 = (i - al * (NC / 4)) * 4; // class of v.x
        const int s  = sstate[al];
        const float pv[4] = {v.x, v.y, v.z, v.w};
        float g = 0.f;
        #pragma unroll
        for (int j = 0; j < 4; ++j) {
            const float p  = fminf(fmaxf(pv[j], 1e-4f), 0.9999f);
            const float om = 1.f - p;
            const float l1 = __logf(om);
            g = __fmaf_rn(p * p, l1, g);
            if ((s < NC) && (c0 + j == s)) {
                const float lp = __logf(p);
                accp += 0.25f * om * om * (-lp) + 0.75f * (p * p) * l1;
            }
        }
        accn += (s != 201) ? g : 0.f;
    };

    if (na_blk == BLK) {
        #pragma unroll 5
        for (int k = 0; k < BLK * (NC / 4) / BLK; ++k)   // 20 fixed iterations
            body(k * BLK + tid);
    } else {
        for (int i = tid; i < na_blk * (NC / 4); i += BLK)
            body(i);
    }

    // ---- Phase 3: block reduction, one float4 store per block ----
    float c = __fmaf_rn(-0.75f, accn, accp);
    float r = reg_acc;
    float p = posf;
    #pragma unroll
    for (int off = 32; off; off >>= 1) {
        c += __shfl_down(c, off);
        r += __shfl_down(r, off);
        p += __shfl_down(p, off);
    }
    const int w = tid >> 6;
    if ((tid & 63) == 0) {
        sred[w * 3 + 0] = c;
        sred[w * 3 + 1] = r;
        sred[w * 3 + 2] = p;
    }
    __syncthreads();
    if (tid == 0) {
        float C = 0.f, R = 0.f, P = 0.f;
        #pragma unroll
        for (int i = 0; i < 4; ++i) {
            C += sred[i * 3 + 0];
            R += sred[i * 3 + 1];
            P += sred[i * 3 + 2];
        }
        parts[b * NBLK + blk] = make_float4(C, R, P, 0.f);
    }
}

__global__ __launch_bounds__(256) void finalize_kernel(
    const float* __restrict__ annots,    // [NB,NM,5]
    const float4* __restrict__ parts,    // [NB*NBLK]
    float* __restrict__ out)
{
    const int tid = threadIdx.x;
    __shared__ float sred[4 * 3];
    __shared__ float simg[NB * 2];

    for (int b = 0; b < NB; ++b) {
        float C = 0.f, R = 0.f, P = 0.f;
        for (int i = tid; i < NBLK; i += 256) {
            const float4 v = parts[b * NBLK + i];
            C += v.x; R += v.y; P += v.z;
        }
        #pragma unroll
        for (int off = 32; off; off >>= 1) {
            C += __shfl_down(C, off);
            R += __shfl_down(R, off);
            P += __shfl_down(P, off);
        }
        if ((tid & 63) == 0) {
            const int w = tid >> 6;
            sred[w * 3 + 0] = C;
            sred[w * 3 + 1] = R;
            sred[w * 3 + 2] = P;
        }
        __syncthreads();
        if (tid == 0) {
            float Ct = 0.f, Rt = 0.f, Pt = 0.f;
            #pragma unroll
            for (int i = 0; i < 4; ++i) {
                Ct += sred[i * 3 + 0];
                Rt += sred[i * 3 + 1];
                Pt += sred[i * 3 + 2];
            }
            bool hv = false;
            for (int m = 0; m < NM; ++m)
                hv = hv || (annots[b * NM * 5 + m * 5 + 4] != -1.0f);
            const float d = fmaxf(Pt, 1.f);
            simg[b * 2 + 0] = hv ? Ct / d : 0.f;
            simg[b * 2 + 1] = (Pt > 0.f) ? Rt / (4.f * d) : 0.f;
        }
        __syncthreads();
    }
    if (tid == 0) {
        float cm = 0.f, rm = 0.f;
        #pragma unroll
        for (int b = 0; b < NB; ++b) {
            cm += simg[b * 2 + 0];
            rm += simg[b * 2 + 1];
        }
        out[0] = cm * (1.f / NB);
        out[1] = rm * (1.f / NB);
    }
}

extern "C" void kernel_launch(void* const* d_in, const int* in_sizes, int n_in,
                              void* d_out, int out_size, void* d_ws, size_t ws_size,
                              hipStream_t stream) {
    const float* cls     = (const float*)d_in[0];  // [NB,NA,NC]
    const float* regs    = (const float*)d_in[1];  // [NB,NA,4]
    const float* anchors = (const float*)d_in[2];  // [1,NA,4]
    const float* annots  = (const float*)d_in[3];  // [NB,NM,5]
    float* out = (float*)d_out;

    float4* parts = (float4*)d_ws;       // NB*NBLK*16 B = 50 KB, fully overwritten

    dim3 g1(NBLK, NB);                   // 3128 blocks
    fused_kernel<<<g1, BLK, 0, stream>>>(cls, regs, anchors, annots, parts);
    finalize_kernel<<<1, 256, 0, stream>>>(annots, parts, out);
}

// Round 4
// 50.299 us; speedup vs baseline: 6.2308x; 2.1009x over previous
//
#include <hip/hip_runtime.h>
#include <cstdint>
#include <cstddef>

// Problem constants (fixed by the reference)
#define NB 8
#define NA 100000
#define NM 32
#define NC 80
#define BLK 256
#define NBLK ((NA + BLK - 1) / BLK)   // 391 blocks per image
#define LN2F 0.69314718056f

// ws layout: float4 parts[NB][NBLK] = {cls_sum, reg_sum, num_pos, 0} per block.
// Every block writes its slot unconditionally -> no zero-init, no atomics.

__global__ __launch_bounds__(256) void fused_kernel(
    const float* __restrict__ cls,       // [NB,NA,NC]
    const float* __restrict__ regs,      // [NB,NA,4]
    const float* __restrict__ anchors,   // [NA,4]
    const float* __restrict__ annots,    // [NB,NM,5]
    float4* __restrict__ parts)          // [NB*NBLK]
{
    const int b   = blockIdx.y;
    const int blk = blockIdx.x;
    const int tid = threadIdx.x;
    const int a   = blk * BLK + tid;

    __shared__ float sann[NM * 5];
    __shared__ float sw[BLK];            // per-anchor negative-term weight (0 or 0.75)
    __shared__ float sred[4 * 3];

    if (tid < NM * 5) sann[tid] = annots[b * NM * 5 + tid];
    __syncthreads();

    // ---- Phase 1: assignment, regression loss, and positive-target correction ----
    float reg_acc = 0.f;
    float posf    = 0.f;
    float corr    = 0.f;   // focal correction at the target element of pos anchors
    int   st      = 201;   // 0..79 pos class, 200 neg, 201 ignore

    if (a < NA) {
        const float4 av = reinterpret_cast<const float4*>(anchors)[a];
        const float ax1 = av.x, ay1 = av.y, ax2 = av.z, ay2 = av.w;
        const float aw = ax2 - ax1, ah = ay2 - ay1;
        const float aarea = aw * ah;

        float best = -1e30f;
        int   barg = 0;
        #pragma unroll
        for (int m = 0; m < NM; ++m) {
            const float bx1 = sann[m * 5 + 0];
            const float by1 = sann[m * 5 + 1];
            const float bx2 = sann[m * 5 + 2];
            const float by2 = sann[m * 5 + 3];
            const float bc  = sann[m * 5 + 4];
            const float area = (bx2 - bx1) * (by2 - by1);
            float iw = fminf(ax2, bx2) - fmaxf(ax1, bx1);
            float ih = fminf(ay2, by2) - fmaxf(ay1, by1);
            iw = fmaxf(iw, 0.f);
            ih = fmaxf(ih, 0.f);
            const float inter = iw * ih;
            const float ua = fmaxf(aarea + area - inter, 1e-8f);
            float iou = inter * __builtin_amdgcn_rcpf(ua);   // feeds thresholds/argmax only
            if (bc == -1.0f) iou = -1.0f;                    // mask padded annotations
            if (iou > best) { best = iou; barg = m; }        // first-max == jnp.argmax
        }

        if (best >= 0.5f) {
            const float bx1 = sann[barg * 5 + 0];
            const float by1 = sann[barg * 5 + 1];
            const float bx2 = sann[barg * 5 + 2];
            const float by2 = sann[barg * 5 + 3];
            st   = (int)sann[barg * 5 + 4];
            posf = 1.f;
            // regression target + smooth-L1
            const float gw  = fmaxf(bx2 - bx1, 0.f);
            const float gh  = fmaxf(by2 - by1, 0.f);
            const float gcx = bx1 + 0.5f * (bx2 - bx1);
            const float gcy = by1 + 0.5f * (by2 - by1);
            const float acx = ax1 + 0.5f * aw;
            const float acy = ay1 + 0.5f * ah;
            const float t0 = ((gcx - acx) / aw) * 10.f;
            const float t1 = ((gcy - acy) / ah) * 10.f;
            const float t2 = __logf(gw / aw) * 5.f;
            const float t3 = __logf(gh / ah) * 5.f;
            const float4 rp = reinterpret_cast<const float4*>(regs)[(size_t)b * NA + a];
            const float d0 = fabsf(t0 - rp.x);
            const float d1 = fabsf(t1 - rp.y);
            const float d2 = fabsf(t2 - rp.z);
            const float d3 = fabsf(t3 - rp.w);
            const float TH = 1.f / 9.f;
            const float C59 = 5.f / 9.f;
            reg_acc  = (d0 <= TH) ? 4.5f * d0 * d0 : d0 - C59;
            reg_acc += (d1 <= TH) ? 4.5f * d1 * d1 : d1 - C59;
            reg_acc += (d2 <= TH) ? 4.5f * d2 * d2 : d2 - C59;
            reg_acc += (d3 <= TH) ? 4.5f * d3 * d3 : d3 - C59;
            // focal correction at the single target element:
            //   +0.25*(1-pt)^2*(-log pt) - 0.75*pt^2*(-log(1-pt))
            const float pr  = cls[((size_t)b * NA + a) * NC + st];
            const float pt  = __builtin_amdgcn_fmed3f(pr, 1e-4f, 0.9999f);
            const float omt = 1.f - pt;
            corr = -0.25f * omt * omt * __logf(pt) + 0.75f * (pt * pt) * __logf(omt);
        } else if (best < 0.4f) {
            st = 200;
        }
    }
    sw[tid] = (st == 201) ? 0.f : 0.75f;   // a>=NA stays 201 -> weight 0
    __syncthreads();

    // ---- Phase 2: branch-free streaming focal scan of this block's 256x80 span ----
    // per element: clamp(med3), om, v_log2, p*p, fma; weight from LDS per float4.
    const int na_blk = min(BLK, NA - blk * BLK);
    const int n4 = na_blk * (NC / 4);
    const float4* __restrict__ p4 =
        reinterpret_cast<const float4*>(cls) + ((size_t)b * NA + (size_t)blk * BLK) * (NC / 4);

    float sneg = 0.f;                    // sum w * p^2 * log2(1-p)  (negative)
    int al  = tid / 20;                  // anchor index of element i = k*BLK+tid
    int rem = tid - al * 20;
    #pragma unroll 5
    for (int k = 0; k < BLK * (NC / 4) / BLK; ++k) {   // 20 iterations
        const int i   = k * BLK + tid;
        const int ild = min(i, n4 - 1);                // clamp (tail block only)
        const float4 v = p4[ild];
        const float wgt = (i < n4) ? sw[al] : 0.f;
        float g = 0.f;
        {
            const float p0 = __builtin_amdgcn_fmed3f(v.x, 1e-4f, 0.9999f);
            g = __fmaf_rn(p0 * p0, __log2f(1.f - p0), g);
            const float p1 = __builtin_amdgcn_fmed3f(v.y, 1e-4f, 0.9999f);
            g = __fmaf_rn(p1 * p1, __log2f(1.f - p1), g);
            const float p2 = __builtin_amdgcn_fmed3f(v.z, 1e-4f, 0.9999f);
            g = __fmaf_rn(p2 * p2, __log2f(1.f - p2), g);
            const float p3 = __builtin_amdgcn_fmed3f(v.w, 1e-4f, 0.9999f);
            g = __fmaf_rn(p3 * p3, __log2f(1.f - p3), g);
        }
        sneg = __fmaf_rn(wgt, g, sneg);
        // incremental al = (i+BLK)/20, rem = (i+BLK)%20   (BLK=256 = 12*20+16)
        rem += 16;
        const int c = (rem >= 20) ? 1 : 0;
        al  += 12 + c;
        rem -= c * 20;
    }

    // cls contribution: corr - ln2 * sneg_total
    float cacc = __fmaf_rn(-LN2F, sneg, corr);

    // ---- Phase 3: block reduction, one float4 store per block ----
    float r = reg_acc;
    float p = posf;
    #pragma unroll
    for (int off = 32; off; off >>= 1) {
        cacc += __shfl_down(cacc, off);
        r    += __shfl_down(r, off);
        p    += __shfl_down(p, off);
    }
    const int w = tid >> 6;
    if ((tid & 63) == 0) {
        sred[w * 3 + 0] = cacc;
        sred[w * 3 + 1] = r;
        sred[w * 3 + 2] = p;
    }
    __syncthreads();
    if (tid == 0) {
        float C = 0.f, R = 0.f, P = 0.f;
        #pragma unroll
        for (int i = 0; i < 4; ++i) {
            C += sred[i * 3 + 0];
            R += sred[i * 3 + 1];
            P += sred[i * 3 + 2];
        }
        parts[b * NBLK + blk] = make_float4(C, R, P, 0.f);
    }
}

__global__ __launch_bounds__(512) void finalize_kernel(
    const float* __restrict__ annots,    // [NB,NM,5]
    const float4* __restrict__ parts,    // [NB*NBLK]
    float* __restrict__ out)
{
    const int tid  = threadIdx.x;
    const int b    = tid >> 6;           // one wave per image
    const int lane = tid & 63;
    __shared__ float simg[NB * 2];

    float C = 0.f, R = 0.f, P = 0.f;
    for (int i = lane; i < NBLK; i += 64) {
        const float4 v = parts[b * NBLK + i];
        C += v.x; R += v.y; P += v.z;
    }
    #pragma unroll
    for (int off = 32; off; off >>= 1) {
        C += __shfl_down(C, off);
        R += __shfl_down(R, off);
        P += __shfl_down(P, off);
    }
    // has_valid via ballot (lanes 0..31 each check one annotation)
    const bool vld = (lane < NM) && (annots[b * NM * 5 + lane * 5 + 4] != -1.0f);
    const unsigned long long m = __ballot(vld);
    if (lane == 0) {
        const bool hv = (m != 0ULL);
        const float d = fmaxf(P, 1.f);
        simg[b * 2 + 0] = hv ? C / d : 0.f;
        simg[b * 2 + 1] = (P > 0.f) ? R / (4.f * d) : 0.f;
    }
    __syncthreads();
    if (tid == 0) {
        float cm = 0.f, rm = 0.f;
        #pragma unroll
        for (int i = 0; i < NB; ++i) {
            cm += simg[i * 2 + 0];
            rm += simg[i * 2 + 1];
        }
        out[0] = cm * (1.f / NB);
        out[1] = rm * (1.f / NB);
    }
}

extern "C" void kernel_launch(void* const* d_in, const int* in_sizes, int n_in,
                              void* d_out, int out_size, void* d_ws, size_t ws_size,
                              hipStream_t stream) {
    const float* cls     = (const float*)d_in[0];  // [NB,NA,NC]
    const float* regs    = (const float*)d_in[1];  // [NB,NA,4]
    const float* anchors = (const float*)d_in[2];  // [1,NA,4]
    const float* annots  = (const float*)d_in[3];  // [NB,NM,5]
    float* out = (float*)d_out;

    float4* parts = (float4*)d_ws;       // NB*NBLK*16 B = 50 KB, fully overwritten

    dim3 g1(NBLK, NB);                   // 3128 blocks
    fused_kernel<<<g1, BLK, 0, stream>>>(cls, regs, anchors, annots, parts);
    finalize_kernel<<<1, 512, 0, stream>>>(annots, parts, out);
}